// Round 2
// baseline (631.304 us; speedup 1.0000x reference)
//
#include <hip/hip_runtime.h>

// ---- problem constants ----
#define SRAD 3
#define TRAD 1
#define Hdim 256
#define Wdim 256
#define Tdim 32
#define CS (Hdim*Wdim*Tdim)   // 2,097,152 elements per channel

// ---- tiling ----
#define TH 8
#define TW 16
#define TT 8
#define HS (TH + 2*SRAD)      // 14
#define WS (TW + 2*SRAD)      // 22
#define TSZ (TT + 2*TRAD)     // 10
#define NPX (HS*WS*TSZ)       // 3080 halo pixels
#define NTHREADS 1024

// LDS layout (bytes): g half2 planes [5][NPX] | e f32 [3][NPX] | v f32 [3][NPX]
//                     | n01 half2 [NPX] | n2 half [NPX]
#define SMEM_BYTES (NPX*50)   // 154,000 B  (<= 160 KiB CU limit)

typedef _Float16 half2_t __attribute__((ext_vector_type(2)));

#if defined(__has_builtin)
#if __has_builtin(__builtin_amdgcn_fdot2)
#define HAVE_FDOT2 1
#else
#define HAVE_FDOT2 0
#endif
#else
#define HAVE_FDOT2 0
#endif

// pack two f32 -> 2x fp16 dword (rtz), type-agnostic carrier
static __device__ __forceinline__ unsigned pack_h2(float a, float b) {
    return __builtin_bit_cast(unsigned, __builtin_amdgcn_cvt_pkrtz(a, b));
}

__global__ __launch_bounds__(NTHREADS) void statden_kernel(
    const float* __restrict__ noisy, const float* __restrict__ guidance,
    const float* __restrict__ est, const float* __restrict__ var,
    const float* __restrict__ sigma_inv, float* __restrict__ out)
{
    extern __shared__ unsigned char smem[];
    unsigned*  gP  = (unsigned*)smem;                  // 5*NPX dwords
    float*     eP  = (float*)(smem + 5*NPX*4);         // 3*NPX
    float*     vP  = (float*)(smem + 8*NPX*4);         // 3*NPX
    unsigned*  nP  = (unsigned*)(smem + 11*NPX*4);     // NPX
    _Float16*  n2P = (_Float16*)(smem + 12*NPX*4);     // NPX halves

    const int tid = threadIdx.x;
    const int h0 = blockIdx.y * TH;
    const int w0 = blockIdx.x * TW;
    const int t0 = blockIdx.z * TT;

    // per-channel sqrt(sigma_inv) for pre-scaled guidance (uniform scalar loads)
    float sq[9];
    #pragma unroll
    for (int c = 0; c < 9; ++c) sq[c] = sqrtf(sigma_inv[c]);

    // ---- stage halo into LDS (zero-fill OOB == reference zero padding) ----
    for (int p = tid; p < NPX; p += NTHREADS) {
        int pt = p % TSZ;
        int q  = p / TSZ;
        int pw = q % WS;
        int ph = q / WS;
        int h = h0 - SRAD + ph;
        int w = w0 - SRAD + pw;
        int t = t0 - TRAD + pt;
        bool ok = ((unsigned)h < (unsigned)Hdim) && ((unsigned)w < (unsigned)Wdim)
               && ((unsigned)t < (unsigned)Tdim);
        int base = (h * Wdim + w) * Tdim + t;

        float g[10];
        #pragma unroll
        for (int c = 0; c < 9; ++c) g[c] = ok ? guidance[c*CS + base] * sq[c] : 0.f;
        g[9] = 0.f;
        #pragma unroll
        for (int j = 0; j < 5; ++j) {
            gP[j*NPX + p] = pack_h2(g[2*j], g[2*j+1]);
        }
        #pragma unroll
        for (int c = 0; c < 3; ++c) {
            eP[c*NPX + p] = ok ? est[c*CS + base] : 0.f;
            vP[c*NPX + p] = ok ? var[c*CS + base] : 0.f;
        }
        float n0 = ok ? noisy[0*CS + base] : 0.f;
        float n1 = ok ? noisy[1*CS + base] : 0.f;
        float n2 = ok ? noisy[2*CS + base] : 0.f;
        nP[p]  = pack_h2(n0, n1);
        n2P[p] = (_Float16)n2;
    }
    __syncthreads();

    // ---- compute: one output pixel per thread ----
    const int tt = tid & 7;
    const int ww = (tid >> 3) & 15;
    const int hh = tid >> 7;
    const int ci = ((hh + SRAD) * WS + (ww + SRAD)) * TSZ + (tt + TRAD);

    half2_t gx[5];
    #pragma unroll
    for (int j = 0; j < 5; ++j) gx[j] = __builtin_bit_cast(half2_t, gP[j*NPX + ci]);
    const float ex0 = eP[ci], ex1 = eP[NPX + ci], ex2 = eP[2*NPX + ci];
    const float vx0 = vP[ci], vx1 = vP[NPX + ci], vx2 = vP[2*NPX + ci];

    const float G2  = 2.9146f * 2.9146f;   // gamma^2
    const float G2E = G2 * 1e-10f;         // gamma^2 * EPS

    float num0 = 0.f, num1 = 0.f, num2 = 0.f, den = 0.f;

    for (int dh = -SRAD; dh <= SRAD; ++dh) {
        const int rb = ci + dh * (WS * TSZ);
        #pragma unroll
        for (int dw = -SRAD; dw <= SRAD; ++dw) {
            #pragma unroll
            for (int dt = -TRAD; dt <= TRAD; ++dt) {
                const int ni = rb + dw * TSZ + dt;

                // guidance distance: sum_c sigma_c * (g_y - g_x)^2, fp16 diffs, fp32 accum
                float dist = 0.f;
                #pragma unroll
                for (int j = 0; j < 5; ++j) {
                    half2_t d = __builtin_bit_cast(half2_t, gP[j*NPX + ni]) - gx[j];
#if HAVE_FDOT2
                    dist = __builtin_amdgcn_fdot2(d, d, dist, false);
#else
                    float dxf = (float)d.x, dyf = (float)d.y;
                    dist = __builtin_fmaf(dxf, dxf, dist);
                    dist = __builtin_fmaf(dyf, dyf, dist);
#endif
                }
                float wj = __expf(-dist);

                // membership: de^2 <= gamma^2 * (v_y + v_x + EPS)  (sqrt/div-free)
                float de0 = eP[ni]         - ex0;
                float de1 = eP[NPX + ni]   - ex1;
                float de2 = eP[2*NPX + ni] - ex2;
                float vs0 = vP[ni]         + vx0;
                float vs1 = vP[NPX + ni]   + vx1;
                float vs2 = vP[2*NPX + ni] + vx2;
                float m0 = __builtin_fmaf(G2, vs0, __builtin_fmaf(-de0, de0, G2E));
                float m1 = __builtin_fmaf(G2, vs1, __builtin_fmaf(-de1, de1, G2E));
                float m2 = __builtin_fmaf(G2, vs2, __builtin_fmaf(-de2, de2, G2E));
                float mn = fminf(fminf(m0, m1), m2);
                float wgt = (mn >= 0.f) ? wj : 0.f;

                half2_t nv = __builtin_bit_cast(half2_t, nP[ni]);
                num0 = __builtin_fmaf(wgt, (float)nv.x, num0);
                num1 = __builtin_fmaf(wgt, (float)nv.y, num1);
                num2 = __builtin_fmaf(wgt, (float)n2P[ni], num2);
                den += wgt;
            }
        }
    }

    const float inv = 1.0f / (den + 1e-10f);
    const int h = h0 + hh, w = w0 + ww, t = t0 + tt;
    const int ob = (h * Wdim + w) * Tdim + t;
    out[0*CS + ob] = num0 * inv;
    out[1*CS + ob] = num1 * inv;
    out[2*CS + ob] = num2 * inv;
}

extern "C" void kernel_launch(void* const* d_in, const int* in_sizes, int n_in,
                              void* d_out, int out_size, void* d_ws, size_t ws_size,
                              hipStream_t stream) {
    const float* noisy    = (const float*)d_in[0];
    const float* guidance = (const float*)d_in[1];
    const float* est      = (const float*)d_in[2];
    const float* var      = (const float*)d_in[3];
    const float* sig      = (const float*)d_in[4];
    float* out = (float*)d_out;

    (void)in_sizes; (void)n_in; (void)out_size; (void)d_ws; (void)ws_size;

    // allow >64KB dynamic LDS (154,000 B); host-side call, not stream-captured
    (void)hipFuncSetAttribute(reinterpret_cast<const void*>(statden_kernel),
                              hipFuncAttributeMaxDynamicSharedMemorySize, SMEM_BYTES);

    dim3 grid(Wdim / TW, Hdim / TH, Tdim / TT);   // (16, 32, 4)
    statden_kernel<<<grid, NTHREADS, SMEM_BYTES, stream>>>(noisy, guidance, est, var, sig, out);
}

// Round 3
// 510.261 us; speedup vs baseline: 1.2372x; 1.2372x over previous
//
#include <hip/hip_runtime.h>

// ---- problem constants ----
#define SRAD 3
#define TRAD 1
#define Hdim 256
#define Wdim 256
#define Tdim 32
#define CS (Hdim*Wdim*Tdim)   // elements per channel

// ---- tiling ----
#define TH 8
#define TW 16
#define TT 8
#define HS (TH + 2*SRAD)      // 14
#define WS (TW + 2*SRAD)      // 22
#define TSZ (TT + 2*TRAD)     // 10
#define NPX (HS*WS*TSZ)       // 3080 halo pixels
#define NTHREADS 512

// LDS: pairA [NPX][2] dw (g0g1,g2g3) | pairB [NPX][2] (g4g5,g6g7)
//    | gn [NPX][2] ((g8,n2),(n0,n1)) | ev[c=0..2][NPX][2] (e_c f32, v_c f32)
#define SMEM_BYTES (NPX * 48)   // 147,840 B  (< 160 KiB)

typedef _Float16 half2_t __attribute__((ext_vector_type(2)));

#if defined(__has_builtin)
#if __has_builtin(__builtin_amdgcn_fdot2)
#define HAVE_FDOT2 1
#else
#define HAVE_FDOT2 0
#endif
#else
#define HAVE_FDOT2 0
#endif

#define G2F  (2.9146f*2.9146f)
#define G2E  (G2F*1e-10f)

static __device__ __forceinline__ unsigned pack_h2(float a, float b) {
    return __builtin_bit_cast(unsigned, __builtin_amdgcn_cvt_pkrtz(a, b));
}
static __device__ __forceinline__ half2_t h2(unsigned u) {
    return __builtin_bit_cast(half2_t, u);
}
static __device__ __forceinline__ float dacc(unsigned y, unsigned x, float acc) {
    half2_t d = h2(y) - h2(x);
#if HAVE_FDOT2
    return __builtin_amdgcn_fdot2(d, d, acc, false);
#else
    float a = (float)d.x, b = (float)d.y;
    return __builtin_fmaf(a, a, __builtin_fmaf(b, b, acc));
#endif
}
// masked: only low half (g8) contributes; high half carries n2
static __device__ __forceinline__ float dacc_lo(unsigned y, unsigned x, float acc) {
    half2_t d = h2(y) - h2(x);
    half2_t dm = h2(__builtin_bit_cast(unsigned, d) & 0xFFFFu);
#if HAVE_FDOT2
    return __builtin_amdgcn_fdot2(dm, dm, acc, false);
#else
    float a = (float)dm.x;
    return __builtin_fmaf(a, a, acc);
#endif
}

struct Win {
    unsigned A[6][2], B[6][2], GN[6][2];
    float E[3][6], V[3][6];
};

static __device__ __forceinline__ void load_win(Win& w, const unsigned* pairA,
        const unsigned* pairB, const unsigned* gnP, const float* evP, int pxo)
{
    const uint4* A4 = (const uint4*)(pairA + 2*pxo);
    uint4 a0 = A4[0], a1 = A4[1], a2 = A4[2];
    w.A[0][0]=a0.x; w.A[0][1]=a0.y; w.A[1][0]=a0.z; w.A[1][1]=a0.w;
    w.A[2][0]=a1.x; w.A[2][1]=a1.y; w.A[3][0]=a1.z; w.A[3][1]=a1.w;
    w.A[4][0]=a2.x; w.A[4][1]=a2.y; w.A[5][0]=a2.z; w.A[5][1]=a2.w;
    const uint4* B4 = (const uint4*)(pairB + 2*pxo);
    uint4 b0 = B4[0], b1 = B4[1], b2 = B4[2];
    w.B[0][0]=b0.x; w.B[0][1]=b0.y; w.B[1][0]=b0.z; w.B[1][1]=b0.w;
    w.B[2][0]=b1.x; w.B[2][1]=b1.y; w.B[3][0]=b1.z; w.B[3][1]=b1.w;
    w.B[4][0]=b2.x; w.B[4][1]=b2.y; w.B[5][0]=b2.z; w.B[5][1]=b2.w;
    const uint4* N4 = (const uint4*)(gnP + 2*pxo);
    uint4 n0 = N4[0], n1 = N4[1], n2 = N4[2];
    w.GN[0][0]=n0.x; w.GN[0][1]=n0.y; w.GN[1][0]=n0.z; w.GN[1][1]=n0.w;
    w.GN[2][0]=n1.x; w.GN[2][1]=n1.y; w.GN[3][0]=n1.z; w.GN[3][1]=n1.w;
    w.GN[4][0]=n2.x; w.GN[4][1]=n2.y; w.GN[5][0]=n2.z; w.GN[5][1]=n2.w;
    #pragma unroll
    for (int c = 0; c < 3; ++c) {
        const float4* E4 = (const float4*)(evP + c*2*NPX + 2*pxo);
        float4 e0 = E4[0], e1 = E4[1], e2 = E4[2];
        w.E[c][0]=e0.x; w.V[c][0]=e0.y; w.E[c][1]=e0.z; w.V[c][1]=e0.w;
        w.E[c][2]=e1.x; w.V[c][2]=e1.y; w.E[c][3]=e1.z; w.V[c][3]=e1.w;
        w.E[c][4]=e2.x; w.V[c][4]=e2.y; w.E[c][5]=e2.z; w.V[c][5]=e2.w;
    }
}

__global__ __launch_bounds__(NTHREADS, 2) void statden_kernel(
    const float* __restrict__ noisy, const float* __restrict__ guidance,
    const float* __restrict__ est, const float* __restrict__ var,
    const float* __restrict__ sigma_inv, float* __restrict__ out)
{
    extern __shared__ unsigned char smem[];
    unsigned* pairA = (unsigned*)smem;
    unsigned* pairB = pairA + 2*NPX;
    unsigned* gnP   = pairB + 2*NPX;
    float*    evP   = (float*)(gnP + 2*NPX);

    const int tid = threadIdx.x;
    const int pix = tid & 255;
    const int sub = tid >> 8;           // checkerboard half
    const int h0 = blockIdx.y * TH;
    const int w0 = blockIdx.x * TW;
    const int t0 = blockIdx.z * TT;

    float sq[9];
    #pragma unroll
    for (int c = 0; c < 9; ++c) sq[c] = sqrtf(sigma_inv[c]);

    // ---- stage halo (zero-fill OOB == reference zero padding) ----
    for (int p = tid; p < NPX; p += NTHREADS) {
        int pt = p % TSZ;
        int q  = p / TSZ;
        int pw = q % WS;
        int ph = q / WS;
        int h = h0 - SRAD + ph;
        int w = w0 - SRAD + pw;
        int t = t0 - TRAD + pt;
        bool ok = ((unsigned)h < (unsigned)Hdim) && ((unsigned)w < (unsigned)Wdim)
               && ((unsigned)t < (unsigned)Tdim);
        int base = (h * Wdim + w) * Tdim + t;

        float g[9];
        #pragma unroll
        for (int c = 0; c < 9; ++c) g[c] = ok ? guidance[c*CS + base] * sq[c] : 0.f;
        float e0 = ok ? est[0*CS + base] : 0.f;
        float e1 = ok ? est[1*CS + base] : 0.f;
        float e2 = ok ? est[2*CS + base] : 0.f;
        float v0 = ok ? var[0*CS + base] : 0.f;
        float v1 = ok ? var[1*CS + base] : 0.f;
        float v2 = ok ? var[2*CS + base] : 0.f;
        float n0 = ok ? noisy[0*CS + base] : 0.f;
        float n1 = ok ? noisy[1*CS + base] : 0.f;
        float n2 = ok ? noisy[2*CS + base] : 0.f;

        uint2 wa; wa.x = pack_h2(g[0], g[1]); wa.y = pack_h2(g[2], g[3]);
        *(uint2*)(pairA + 2*p) = wa;
        uint2 wb; wb.x = pack_h2(g[4], g[5]); wb.y = pack_h2(g[6], g[7]);
        *(uint2*)(pairB + 2*p) = wb;
        uint2 wn; wn.x = pack_h2(g[8], n2);   wn.y = pack_h2(n0, n1);
        *(uint2*)(gnP + 2*p) = wn;
        float2 ev;
        ev.x = e0; ev.y = v0; *(float2*)(evP + 0*2*NPX + 2*p) = ev;
        ev.x = e1; ev.y = v1; *(float2*)(evP + 1*2*NPX + 2*p) = ev;
        ev.x = e2; ev.y = v2; *(float2*)(evP + 2*2*NPX + 2*p) = ev;
    }
    __syncthreads();

    // ---- per-thread output column: 4 consecutive t outputs ----
    const int tfh = pix & 1;
    const int ww  = (pix >> 1) & 15;
    const int hh  = pix >> 5;
    const int col = ((hh + SRAD) * WS + (ww + SRAD)) * TSZ + 4 * tfh; // window start px

    // centers (output j at window t-pos j+1)
    Win cw;
    load_win(cw, pairA, pairB, gnP, evP, col);
    unsigned ax0[4], ax1[4], bx0[4], bx1[4], gx8[4];
    float ex[4][3], Kx[4][3];
    #pragma unroll
    for (int j = 0; j < 4; ++j) {
        ax0[j] = cw.A[j+1][0]; ax1[j] = cw.A[j+1][1];
        bx0[j] = cw.B[j+1][0]; bx1[j] = cw.B[j+1][1];
        gx8[j] = cw.GN[j+1][0];
        #pragma unroll
        for (int c = 0; c < 3; ++c) {
            ex[j][c] = cw.E[c][j+1];
            Kx[j][c] = __builtin_fmaf(G2F, cw.V[c][j+1], G2E);
        }
    }

    float nm[3][4] = {{0.f,0.f,0.f,0.f},{0.f,0.f,0.f,0.f},{0.f,0.f,0.f,0.f}};
    float den[4]   = {0.f,0.f,0.f,0.f};

    #pragma unroll 1
    for (int dh = -SRAD; dh <= SRAD; ++dh) {
        #pragma unroll 1
        for (int dw = -SRAD; dw <= SRAD; ++dw) {
            if (((dh + dw + sub) & 1) != 0) continue;   // wave-uniform split
            const int pxo = col + dh * (WS * TSZ) + dw * TSZ;
            Win wv;
            load_win(wv, pairA, pairB, gnP, evP, pxo);

            float Gv[3][6];
            #pragma unroll
            for (int c = 0; c < 3; ++c)
                #pragma unroll
                for (int tp = 0; tp < 6; ++tp) Gv[c][tp] = G2F * wv.V[c][tp];
            float n0f[6], n1f[6], n2f[6];
            #pragma unroll
            for (int tp = 0; tp < 6; ++tp) {
                half2_t nh = h2(wv.GN[tp][1]);
                n0f[tp] = (float)nh.x; n1f[tp] = (float)nh.y;
                half2_t gh = h2(wv.GN[tp][0]);
                n2f[tp] = (float)gh.y;
            }

            #pragma unroll
            for (int j = 0; j < 4; ++j) {
                #pragma unroll
                for (int dt = -TRAD; dt <= TRAD; ++dt) {
                    const int tp = j + dt + 1;
                    float dist = dacc(wv.A[tp][0], ax0[j], 0.f);
                    dist = dacc(wv.A[tp][1], ax1[j], dist);
                    dist = dacc(wv.B[tp][0], bx0[j], dist);
                    dist = dacc(wv.B[tp][1], bx1[j], dist);
                    dist = dacc_lo(wv.GN[tp][0], gx8[j], dist);
                    float wj = __expf(-dist);

                    float de0 = wv.E[0][tp] - ex[j][0];
                    float de1 = wv.E[1][tp] - ex[j][1];
                    float de2 = wv.E[2][tp] - ex[j][2];
                    float m0 = __builtin_fmaf(-de0, de0, Gv[0][tp] + Kx[j][0]);
                    float m1 = __builtin_fmaf(-de1, de1, Gv[1][tp] + Kx[j][1]);
                    float m2 = __builtin_fmaf(-de2, de2, Gv[2][tp] + Kx[j][2]);
                    float mn = fminf(fminf(m0, m1), m2);
                    float wgt = (mn >= 0.f) ? wj : 0.f;

                    nm[0][j] = __builtin_fmaf(wgt, n0f[tp], nm[0][j]);
                    nm[1][j] = __builtin_fmaf(wgt, n1f[tp], nm[1][j]);
                    nm[2][j] = __builtin_fmaf(wgt, n2f[tp], nm[2][j]);
                    den[j] += wgt;
                }
            }
        }
    }

    // ---- combine the two checkerboard halves via LDS ----
    __syncthreads();
    float* red = (float*)smem;   // 16 * 256 * 4 = 16 KB, reuse
    if (sub == 1) {
        #pragma unroll
        for (int c = 0; c < 3; ++c)
            #pragma unroll
            for (int j = 0; j < 4; ++j) red[(c*4 + j)*256 + pix] = nm[c][j];
        #pragma unroll
        for (int j = 0; j < 4; ++j) red[(12 + j)*256 + pix] = den[j];
    }
    __syncthreads();
    if (sub == 0) {
        #pragma unroll
        for (int c = 0; c < 3; ++c)
            #pragma unroll
            for (int j = 0; j < 4; ++j) nm[c][j] += red[(c*4 + j)*256 + pix];
        float inv[4];
        #pragma unroll
        for (int j = 0; j < 4; ++j)
            inv[j] = 1.0f / (den[j] + red[(12 + j)*256 + pix] + 1e-10f);

        const int hG = h0 + hh, wG = w0 + ww;
        const int ob = (hG * Wdim + wG) * Tdim + t0 + 4 * tfh;
        #pragma unroll
        for (int c = 0; c < 3; ++c) {
            float4 o;
            o.x = nm[c][0] * inv[0];
            o.y = nm[c][1] * inv[1];
            o.z = nm[c][2] * inv[2];
            o.w = nm[c][3] * inv[3];
            *(float4*)(out + c*CS + ob) = o;
        }
    }
}

extern "C" void kernel_launch(void* const* d_in, const int* in_sizes, int n_in,
                              void* d_out, int out_size, void* d_ws, size_t ws_size,
                              hipStream_t stream) {
    const float* noisy    = (const float*)d_in[0];
    const float* guidance = (const float*)d_in[1];
    const float* est      = (const float*)d_in[2];
    const float* var      = (const float*)d_in[3];
    const float* sig      = (const float*)d_in[4];
    float* out = (float*)d_out;

    (void)in_sizes; (void)n_in; (void)out_size; (void)d_ws; (void)ws_size;

    (void)hipFuncSetAttribute(reinterpret_cast<const void*>(statden_kernel),
                              hipFuncAttributeMaxDynamicSharedMemorySize, SMEM_BYTES);

    dim3 grid(Wdim / TW, Hdim / TH, Tdim / TT);   // (16, 32, 4)
    statden_kernel<<<grid, NTHREADS, SMEM_BYTES, stream>>>(noisy, guidance, est, var, sig, out);
}